// Round 14
// baseline (99.578 us; speedup 1.0000x reference)
//
#include <hip/hip_runtime.h>
#include <stdint.h>

// LIF forward scan: u = 0.5*u + x[t] - 0.5*o ; o = (u - 0.5 > 0) ? 1 : 0
// x: [32, 8192, 200] f32, time contiguous. 262144 independent rows.
//
// R14 = R13 with HALF the LDS so ALL blocks are resident (the one variable).
// R12 (depth-1) == R13 (depth-3) at ~96us proved pipeline depth irrelevant;
// occupancy read 18% (~6 waves/CU avg) because 32KB/block capped residency
// at 5 of the grid's 8 blocks/CU. Now: 2 bufs x 4KB per wave = 16KB/block
// -> capacity 10 > 8 -> all 8 blocks (16 waves/CU, 50%) resident from t=0.
//  - copy-shaped gll loads: each inst = 16 rows x 64B = 16 full aligned
//    lines; loads-only vmcnt queue (stores all deferred via bit-pack);
//    counted WAITV(4) retires exactly the scanned chunk's batch.
//  - fma scan (bit-identical: 0.5*u and o*Vth exact products);
//    both-sides swizzle slot(r,c)=r*4+(c^((r>>1)&3)) matches pre-swizzled
//    gll source seg (l&3)^((l>>3)&3).
//  - store phase: bits -> wave-private LDS -> 50 contiguous 1KB stores
//    (WRITE measured ideal 204800KB in R11-R13).
//  - no barriers (wave-private LDS), no register pipelines.

#define STEPS 200
#define TPB 128   // 2 waves/block; 16 KB LDS -> 10 blocks/CU capacity

typedef __attribute__((address_space(3))) uint32_t lds_u32;
typedef __attribute__((address_space(1))) const uint32_t glb_u32;

#define WAITV(n) do { asm volatile("s_waitcnt vmcnt(" #n ")" ::: "memory"); \
                      __builtin_amdgcn_sched_barrier(0); } while (0)

// one step: t = fma(0.5,u,x); u = t - d; d = spike ? 0.5 : 0; bit into m
__device__ __forceinline__ void lif1(float xi, float& u, float& d,
                                     uint32_t& m, uint32_t bit) {
    float t = __fmaf_rn(0.5f, u, xi);
    u = __fsub_rn(t, d);
    bool sp = (u > 0.5f);
    d = sp ? 0.5f : 0.0f;
    m |= sp ? bit : 0u;
}

// stage one 16-step chunk (4KB): 4 gll, each = 16 rows x 64B stripes
__device__ __forceinline__ void stage16(const float* __restrict__ src_base,
                                        float4* buf, int t0) {
#pragma unroll
    for (int i = 0; i < 4; ++i)
        __builtin_amdgcn_global_load_lds((const glb_u32*)(src_base + i * 16 * STEPS + t0),
                                         (lds_u32*)(buf + i * 64), 16, 0, 0);
}

// tail: 8 steps, 2 gll (rows 32i + (l>>1), seg l&1, t0=192; linear layout)
__device__ __forceinline__ void stage8(const float* __restrict__ srcT,
                                       float4* buf) {
#pragma unroll
    for (int i = 0; i < 2; ++i)
        __builtin_amdgcn_global_load_lds((const glb_u32*)(srcT + i * 32 * STEPS),
                                         (lds_u32*)(buf + i * 64), 16, 0, 0);
}

// scan one 16-step chunk for row `lane` -> 16-bit spike mask
__device__ __forceinline__ uint32_t scan16(const float4* buf, int lane,
                                           float& u, float& d) {
    const int sw = (lane >> 1) & 3;
    float4 rx[4];
#pragma unroll
    for (int c = 0; c < 4; ++c)
        rx[c] = buf[lane * 4 + (c ^ sw)];
    uint32_t m = 0;
#pragma unroll
    for (int g = 0; g < 4; ++g) {
        lif1(rx[g].x, u, d, m, 1u << (4 * g + 0));
        lif1(rx[g].y, u, d, m, 1u << (4 * g + 1));
        lif1(rx[g].z, u, d, m, 1u << (4 * g + 2));
        lif1(rx[g].w, u, d, m, 1u << (4 * g + 3));
    }
    return m;
}

__device__ __forceinline__ uint32_t scan8(const float4* buf, int lane,
                                          float& u, float& d) {
    float4 r0 = buf[lane * 2 + 0];
    float4 r1 = buf[lane * 2 + 1];
    uint32_t m = 0;
    lif1(r0.x, u, d, m, 1u);   lif1(r0.y, u, d, m, 2u);
    lif1(r0.z, u, d, m, 4u);   lif1(r0.w, u, d, m, 8u);
    lif1(r1.x, u, d, m, 16u);  lif1(r1.y, u, d, m, 32u);
    lif1(r1.z, u, d, m, 64u);  lif1(r1.w, u, d, m, 128u);
    return m;
}

__global__ __launch_bounds__(TPB) void lif_kernel(const float* __restrict__ x,
                                                  float* __restrict__ out)
{
    __shared__ float4 tile[2 * 2 * 256];           // 2 waves x 2 bufs x 4KB = 16KB
    const int tid = threadIdx.x;
    const int w = tid >> 6, lane = tid & 63;
    const long long wrow0 = (long long)blockIdx.x * TPB + w * 64;
    const float* xb = x + wrow0 * STEPS;
    float4* A = tile + w * 512;
    float4* Bb = tile + w * 512 + 256;

    // per-lane pre-swizzled source bases
    const float* srcS = xb + (lane >> 2) * STEPS + (((lane & 3) ^ ((lane >> 3) & 3)) << 2);
    const float* srcT = xb + (lane >> 1) * STEPS + ((lane & 1) << 2) + 192;

    float u = 0.0f, d = 0.0f;                      // d = o*Vth in {0, 0.5}
    uint32_t w0, w1, w2, w3, w4, w5, w6;

    // prologue: both buffers in flight (8 gll)
    stage16(srcS, A, 0);
    stage16(srcS, Bb, 16);

    // steady: WAITV(4) retires the scanned chunk; restage same buf after scan
    WAITV(4); w0  = scan16(A,  lane, u, d);        stage16(srcS, A, 32);
    WAITV(4); w0 |= scan16(Bb, lane, u, d) << 16;  stage16(srcS, Bb, 48);
    WAITV(4); w1  = scan16(A,  lane, u, d);        stage16(srcS, A, 64);
    WAITV(4); w1 |= scan16(Bb, lane, u, d) << 16;  stage16(srcS, Bb, 80);
    WAITV(4); w2  = scan16(A,  lane, u, d);        stage16(srcS, A, 96);
    WAITV(4); w2 |= scan16(Bb, lane, u, d) << 16;  stage16(srcS, Bb, 112);
    WAITV(4); w3  = scan16(A,  lane, u, d);        stage16(srcS, A, 128);
    WAITV(4); w3 |= scan16(Bb, lane, u, d) << 16;  stage16(srcS, Bb, 144);
    WAITV(4); w4  = scan16(A,  lane, u, d);        stage16(srcS, A, 160);
    WAITV(4); w4 |= scan16(Bb, lane, u, d) << 16;  stage16(srcS, Bb, 176);
    WAITV(4); w5  = scan16(A,  lane, u, d);        stage8(srcT, A);   // tail
    WAITV(2); w5 |= scan16(Bb, lane, u, d) << 16;
    WAITV(0); w6  = scan8(A, lane, u, d);

    // ---- store phase: bits -> wave-private LDS -> 50 contiguous 1KB stores ----
    uint32_t* bits = reinterpret_cast<uint32_t*>(Bb);  // 64 rows x 8 u32 (2KB)
    bits[lane * 8 + 0] = w0; bits[lane * 8 + 1] = w1; bits[lane * 8 + 2] = w2;
    bits[lane * 8 + 3] = w3; bits[lane * 8 + 4] = w4; bits[lane * 8 + 5] = w5;
    bits[lane * 8 + 6] = w6;
    // same-wave DS ordering + compiler lgkmcnt: no barrier needed

    float* ob = out + wrow0 * STEPS;               // wave's 50KB output
#pragma unroll
    for (int s = 0; s < 50; ++s) {
        int f = s * 64 + lane;                     // float4 index in wave region
        int r = f / 50;                            // row (magic-mul)
        int c = f - r * 50;                        // segment 0..49 (4 steps)
        uint32_t wd = bits[r * 8 + (c >> 3)] >> (((c >> 2) & 1) * 16 + (c & 3) * 4);
        float4 v;
        v.x = (wd & 1u) ? 1.0f : 0.0f;
        v.y = (wd & 2u) ? 1.0f : 0.0f;
        v.z = (wd & 4u) ? 1.0f : 0.0f;
        v.w = (wd & 8u) ? 1.0f : 0.0f;
        *reinterpret_cast<float4*>(ob + f * 4) = v;   // contiguous: base + 16B*f
    }
}

extern "C" void kernel_launch(void* const* d_in, const int* in_sizes, int n_in,
                              void* d_out, int out_size, void* d_ws, size_t ws_size,
                              hipStream_t stream)
{
    const float* x = (const float*)d_in[0];
    float* out = (float*)d_out;
    int nrows = in_sizes[0] / STEPS;       // 262144
    int grid = nrows / TPB;                // 2048 blocks of 2 waves = 8/CU
    lif_kernel<<<grid, TPB, 0, stream>>>(x, out);
}

// Round 16
// 74.023 us; speedup vs baseline: 1.3452x; 1.3452x over previous
//
#include <hip/hip_runtime.h>
#include <stdint.h>

// LIF forward scan: u = 0.5*u + x[t] - 0.5*o ; o = (u - 0.5 > 0) ? 1 : 0
// x: [32, 8192, 200] f32, time contiguous. 262144 independent rows.
//
// R16 = R15 with the compile fix: __builtin_nontemporal_store requires a
// native clang vector pointer (ext_vector_type), not HIP's float4 class.
// Theory unchanged (single variable vs R13's 95.4us): output writes
// allocate in L2/L3 and evict the read-only 200MB input (R14: FETCH rose
// 126->183MB with residency); nt stores (no-alloc) should let the input
// stay L3-resident across graph replays -> FETCH drops sharply, reads
// served at L3 BW, HBM traffic approaches write-only.
//  - everything else identical to R13: 16-step chunks, 4 wave-private bufs,
//    depth-3 gll pipeline (copy-shaped: 16 full 64B lines per inst),
//    loads-only vmcnt queue with counted WAITV, fma scan (bit-identical),
//    bit-packed spikes, 50 contiguous 1KB stores per wave.

#define STEPS 200
#define TPB 128   // 2 waves/block; 32 KB LDS -> 5 blocks/CU

typedef __attribute__((address_space(3))) uint32_t lds_u32;
typedef __attribute__((address_space(1))) const uint32_t glb_u32;
typedef __attribute__((ext_vector_type(4))) float f32x4;   // native vector for nt store

#define WAITV(n) do { asm volatile("s_waitcnt vmcnt(" #n ")" ::: "memory"); \
                      __builtin_amdgcn_sched_barrier(0); } while (0)

// one step: t = fma(0.5,u,x); u = t - d; d = spike ? 0.5 : 0; bit into m
__device__ __forceinline__ void lif1(float xi, float& u, float& d,
                                     uint32_t& m, uint32_t bit) {
    float t = __fmaf_rn(0.5f, u, xi);
    u = __fsub_rn(t, d);
    bool sp = (u > 0.5f);
    d = sp ? 0.5f : 0.0f;
    m |= sp ? bit : 0u;
}

// stage one 16-step chunk: 4 gll, each covering rows 16i..16i+15's
// contiguous 64B stripes (16 full lines). src_base is per-lane pre-swizzled.
__device__ __forceinline__ void stage16(const float* __restrict__ src_base,
                                        float4* buf, int t0) {
#pragma unroll
    for (int i = 0; i < 4; ++i)
        __builtin_amdgcn_global_load_lds((const glb_u32*)(src_base + i * 16 * STEPS + t0),
                                         (lds_u32*)(buf + i * 64), 16, 0, 0);
}

// tail: 8 steps, 2 gll (rows 32i + (l>>1), seg l&1, t0=192; linear layout)
__device__ __forceinline__ void stage8(const float* __restrict__ srcT,
                                       float4* buf) {
#pragma unroll
    for (int i = 0; i < 2; ++i)
        __builtin_amdgcn_global_load_lds((const glb_u32*)(srcT + i * 32 * STEPS),
                                         (lds_u32*)(buf + i * 64), 16, 0, 0);
}

// scan one 16-step chunk for row `lane` -> 16-bit spike mask
__device__ __forceinline__ uint32_t scan16(const float4* buf, int lane,
                                           float& u, float& d) {
    const int sw = (lane >> 1) & 3;
    float4 rx[4];
#pragma unroll
    for (int c = 0; c < 4; ++c)
        rx[c] = buf[lane * 4 + (c ^ sw)];
    uint32_t m = 0;
#pragma unroll
    for (int g = 0; g < 4; ++g) {
        lif1(rx[g].x, u, d, m, 1u << (4 * g + 0));
        lif1(rx[g].y, u, d, m, 1u << (4 * g + 1));
        lif1(rx[g].z, u, d, m, 1u << (4 * g + 2));
        lif1(rx[g].w, u, d, m, 1u << (4 * g + 3));
    }
    return m;
}

__device__ __forceinline__ uint32_t scan8(const float4* buf, int lane,
                                          float& u, float& d) {
    float4 r0 = buf[lane * 2 + 0];
    float4 r1 = buf[lane * 2 + 1];
    uint32_t m = 0;
    lif1(r0.x, u, d, m, 1u);   lif1(r0.y, u, d, m, 2u);
    lif1(r0.z, u, d, m, 4u);   lif1(r0.w, u, d, m, 8u);
    lif1(r1.x, u, d, m, 16u);  lif1(r1.y, u, d, m, 32u);
    lif1(r1.z, u, d, m, 64u);  lif1(r1.w, u, d, m, 128u);
    return m;
}

__global__ __launch_bounds__(TPB) void lif_kernel(const float* __restrict__ x,
                                                  float* __restrict__ out)
{
    __shared__ float4 tile[2 * 4 * 256];           // 2 waves x 4 bufs x 4KB = 32KB
    const int tid = threadIdx.x;
    const int w = tid >> 6, lane = tid & 63;
    const long long wrow0 = (long long)blockIdx.x * TPB + w * 64;
    const float* xb = x + wrow0 * STEPS;
    float4* B[4] = { tile + w * 1024,        tile + w * 1024 + 256,
                     tile + w * 1024 + 512,  tile + w * 1024 + 768 };

    // per-lane pre-swizzled source bases
    const float* srcS = xb + (lane >> 2) * STEPS + (((lane & 3) ^ ((lane >> 3) & 3)) << 2);
    const float* srcT = xb + (lane >> 1) * STEPS + ((lane & 1) << 2) + 192;

    float u = 0.0f, d = 0.0f;                      // d = o*Vth in {0, 0.5}
    uint32_t w0, w1, w2, w3, w4, w5, w6;

    // prologue: 3 chunks in flight (12 gll)
    stage16(srcS, B[0], 0);
    stage16(srcS, B[1], 16);
    stage16(srcS, B[2], 32);

    // steady: stage ch+3, WAITV(12) retires ch (queue holds ONLY loads)
    stage16(srcS, B[3], 48);   WAITV(12); w0  = scan16(B[0], lane, u, d);
    stage16(srcS, B[0], 64);   WAITV(12); w0 |= scan16(B[1], lane, u, d) << 16;
    stage16(srcS, B[1], 80);   WAITV(12); w1  = scan16(B[2], lane, u, d);
    stage16(srcS, B[2], 96);   WAITV(12); w1 |= scan16(B[3], lane, u, d) << 16;
    stage16(srcS, B[3], 112);  WAITV(12); w2  = scan16(B[0], lane, u, d);
    stage16(srcS, B[0], 128);  WAITV(12); w2 |= scan16(B[1], lane, u, d) << 16;
    stage16(srcS, B[1], 144);  WAITV(12); w3  = scan16(B[2], lane, u, d);
    stage16(srcS, B[2], 160);  WAITV(12); w3 |= scan16(B[3], lane, u, d) << 16;
    stage16(srcS, B[3], 176);  WAITV(12); w4  = scan16(B[0], lane, u, d);
    stage8(srcT, B[0]);        WAITV(10); w4 |= scan16(B[1], lane, u, d) << 16;
                               WAITV(6);  w5  = scan16(B[2], lane, u, d);
                               WAITV(2);  w5 |= scan16(B[3], lane, u, d) << 16;
                               WAITV(0);  w6  = scan8(B[0], lane, u, d);

    // ---- store phase: bits -> wave-private LDS -> 50 contiguous 1KB nt stores ----
    uint32_t* bits = reinterpret_cast<uint32_t*>(B[1]);  // 64 rows x 8 u32
    bits[lane * 8 + 0] = w0; bits[lane * 8 + 1] = w1; bits[lane * 8 + 2] = w2;
    bits[lane * 8 + 3] = w3; bits[lane * 8 + 4] = w4; bits[lane * 8 + 5] = w5;
    bits[lane * 8 + 6] = w6;
    // same-wave DS ordering + compiler lgkmcnt: no barrier needed

    float* ob = out + wrow0 * STEPS;               // wave's 50KB output
#pragma unroll
    for (int s = 0; s < 50; ++s) {
        int f = s * 64 + lane;                     // float4 index in wave region
        int r = f / 50;                            // row (magic-mul)
        int c = f - r * 50;                        // segment 0..49 (4 steps)
        uint32_t wd = bits[r * 8 + (c >> 3)] >> (((c >> 2) & 1) * 16 + (c & 3) * 4);
        f32x4 v;
        v.x = (wd & 1u) ? 1.0f : 0.0f;
        v.y = (wd & 2u) ? 1.0f : 0.0f;
        v.z = (wd & 4u) ? 1.0f : 0.0f;
        v.w = (wd & 8u) ? 1.0f : 0.0f;
        // NON-TEMPORAL (no-alloc): write stream stops evicting the
        // read-only input from L2/L3 between graph replays.
        __builtin_nontemporal_store(v, reinterpret_cast<f32x4*>(ob + f * 4));
    }
}

extern "C" void kernel_launch(void* const* d_in, const int* in_sizes, int n_in,
                              void* d_out, int out_size, void* d_ws, size_t ws_size,
                              hipStream_t stream)
{
    const float* x = (const float*)d_in[0];
    float* out = (float*)d_out;
    int nrows = in_sizes[0] / STEPS;       // 262144
    int grid = nrows / TPB;                // 2048 blocks of 2 waves
    lif_kernel<<<grid, TPB, 0, stream>>>(x, out);
}